// Round 9
// baseline (155.197 us; speedup 1.0000x reference)
//
#include <hip/hip_runtime.h>

#define T_LEN  4096
#define BATCHN 32
#define NROWS  (T_LEN*BATCHN)   // 131072
#define CHUNKL 64
#define NCHUNK (T_LEN/CHUNKL)   // 64

// LDS row strides (floats). s_in rows hold 48 payload floats:
//   [0..15]  = B_n/C_n interleaved ([2n]=B_n, [2n+1]=C_n)
//   [16+4h+0/1] = x*dt (p=0/1), [16+4h+2] = dA, [16+4h+3] = pad   (h=0..7 -> up to [47])
// stride 52 = 48 + 4 pad: 208B keeps 16B alignment; 52%32=20 spreads banks.
#define SIN_STRIDE 52
#define SY_STRIDE  28

typedef float4 f4;

__device__ __forceinline__ float fsilu(float x){ return x / (1.f + __expf(-x)); }
__device__ __forceinline__ float fsoftplus(float x){ return (x > 20.f) ? x : log1pf(__expf(x)); }

// 8-lane group sum via xor butterfly (groups = lanes [8k..8k+7]); direction-free.
__device__ __forceinline__ float group8_sum(float v){
  v += __shfl_xor(v, 1);
  v += __shfl_xor(v, 2);
  v += __shfl_xor(v, 4);
  return v;
}

// ---------------- K1: per-row input proj ----------------
// row r = t*32 + b. obs(T,B,32) -> x=relu(obs@W_in^T+b_in) -> zxbcdt = x@in_proj^T
// writes z[r][16], xbc_pre[r][32], dt[r][8] (post-softplus)
__global__ __launch_bounds__(256) void k1_proj(
    const float* __restrict__ obs, const float* __restrict__ W_in,
    const float* __restrict__ b_in, const float* __restrict__ in_proj,
    const float* __restrict__ dt_bias,
    float* __restrict__ z_g, float* __restrict__ xbc_g, float* __restrict__ dt_g)
{
  int r = blockIdx.x*256 + threadIdx.x;
  float o[32];
  const f4* op = (const f4*)(obs + (size_t)r*32);
  #pragma unroll
  for (int j=0;j<8;j++){ f4 v = op[j]; o[4*j]=v.x; o[4*j+1]=v.y; o[4*j+2]=v.z; o[4*j+3]=v.w; }
  float x[16];
  #pragma unroll
  for (int i=0;i<16;i++){
    float a = b_in[i];
    #pragma unroll
    for (int k=0;k<32;k++) a += o[k]*W_in[i*32+k];
    x[i] = a > 0.f ? a : 0.f;
  }
  float acc[56];
  #pragma unroll
  for (int j=0;j<56;j++){
    float a = 0.f;
    #pragma unroll
    for (int k=0;k<16;k++) a += x[k]*in_proj[j*16+k];
    acc[j] = a;
  }
  f4* zo = (f4*)(z_g + (size_t)r*16);
  #pragma unroll
  for (int j=0;j<4;j++) zo[j] = make_float4(acc[4*j],acc[4*j+1],acc[4*j+2],acc[4*j+3]);
  f4* xo = (f4*)(xbc_g + (size_t)r*32);
  #pragma unroll
  for (int j=0;j<8;j++) xo[j] = make_float4(acc[16+4*j],acc[17+4*j],acc[18+4*j],acc[19+4*j]);
  float dtv[8];
  #pragma unroll
  for (int k=0;k<8;k++) dtv[k] = fsoftplus(acc[48+k] + dt_bias[k]);
  f4* dto = (f4*)(dt_g + (size_t)r*8);
  dto[0] = make_float4(dtv[0],dtv[1],dtv[2],dtv[3]);
  dto[1] = make_float4(dtv[4],dtv[5],dtv[6],dtv[7]);
}

// ---------------- K2: conv+silu precompute + within-chunk scan ----------------
// one wave per (b, chunk). Staging: lane = timestep. Scan: lane = h*8+n.
__global__ __launch_bounds__(64) void k2_scan(
    const float* __restrict__ xbc_g, const float* __restrict__ dt_g,
    const float* __restrict__ conv_w, const float* __restrict__ conv_b,
    const float* __restrict__ A_log, const float* __restrict__ D_skip,
    float* __restrict__ yl_g, float* __restrict__ ea_g, float* __restrict__ cm_g,
    float* __restrict__ sloc_g, float* __restrict__ p_g)
{
  __shared__ float s_in[CHUNKL*SIN_STRIDE];
  __shared__ float s_y[CHUNKL*SY_STRIDE];   // [2h],[2h+1]=y ; [16+h]=exp(cumA)
  int bid = blockIdx.x;
  int b = bid & 31, c = bid >> 5;
  int l = threadIdx.x;
  int t = c*CHUNKL + l;
  size_t r = (size_t)t*BATCHN + b;

  // ---- staging: this lane owns row t ----
  float xb[32], pv[32], dtv[8];
  {
    const f4* xp = (const f4*)(xbc_g + r*32);
    #pragma unroll
    for (int j=0;j<8;j++){ f4 v=xp[j]; xb[4*j]=v.x; xb[4*j+1]=v.y; xb[4*j+2]=v.z; xb[4*j+3]=v.w; }
    if (t == 0) {
      #pragma unroll
      for (int j=0;j<32;j++) pv[j]=0.f;
    } else {
      const f4* pp = (const f4*)(xbc_g + (r-BATCHN)*32);
      #pragma unroll
      for (int j=0;j<8;j++){ f4 v=pp[j]; pv[4*j]=v.x; pv[4*j+1]=v.y; pv[4*j+2]=v.z; pv[4*j+3]=v.w; }
    }
    const f4* dp = (const f4*)(dt_g + r*8);
    f4 d0=dp[0], d1=dp[1];
    dtv[0]=d0.x; dtv[1]=d0.y; dtv[2]=d0.z; dtv[3]=d0.w;
    dtv[4]=d1.x; dtv[5]=d1.y; dtv[6]=d1.z; dtv[7]=d1.w;
  }
  float sv[32];
  #pragma unroll
  for (int ch=0; ch<32; ch++){
    float cv = conv_b[ch] + pv[ch]*conv_w[ch*2] + xb[ch]*conv_w[ch*2+1];
    sv[ch] = fsilu(cv);
  }
  float xskip[16], cmv[8];
  #pragma unroll
  for (int i=0;i<16;i++) xskip[i] = sv[i]*D_skip[i>>1];
  #pragma unroll
  for (int n=0;n<8;n++) cmv[n] = sv[24+n];
  {
    float row[48];                          // FIX: was row[32] — layout needs 48 floats
    #pragma unroll
    for (int n=0;n<8;n++){ row[2*n]=sv[16+n]; row[2*n+1]=sv[24+n]; }
    #pragma unroll
    for (int h=0;h<8;h++){
      float dth = dtv[h];
      row[16+4*h]   = sv[2*h]*dth;
      row[16+4*h+1] = sv[2*h+1]*dth;
      row[16+4*h+2] = __expf(-__expf(A_log[h])*dth);
      row[16+4*h+3] = 0.f;
    }
    f4* sr = (f4*)&s_in[l*SIN_STRIDE];
    #pragma unroll
    for (int j=0;j<12;j++) sr[j] = make_float4(row[4*j],row[4*j+1],row[4*j+2],row[4*j+3]);  // FIX: 12 f4s, was 8
  }
  __syncthreads();

  // ---- scan: lane = h*8 + n ----
  int h = l >> 3, n = l & 7;
  float s0=0.f, s1=0.f, ep=1.f;
  #pragma unroll 8
  for (int tt=0; tt<CHUNKL; tt++){
    float2 bcv = *(const float2*)&s_in[tt*SIN_STRIDE + 2*n];   // B_n, C_n (broadcast across h)
    f4 xd = *(const f4*)&s_in[tt*SIN_STRIDE + 16 + 4*h];       // xdt0, xdt1, dA, pad
    s0 = xd.z*s0 + xd.x*bcv.x;
    s1 = xd.z*s1 + xd.y*bcv.x;
    // reduce C·s over the 8 n-lanes of this head via xor butterfly (direction-free)
    float y0 = group8_sum(s0*bcv.y);
    float y1 = group8_sum(s1*bcv.y);
    ep *= xd.z;
    if (n == 0){
      *(float2*)&s_y[tt*SY_STRIDE + 2*h] = make_float2(y0, y1);
      s_y[tt*SY_STRIDE + 16 + h] = ep;
    }
  }
  // final chunk state + decay product
  {
    size_t sb = ((size_t)(c*32+b)*8 + h)*16 + n;
    sloc_g[sb]   = s0;
    sloc_g[sb+8] = s1;
    if (n == 0) p_g[(size_t)(c*32+b)*8 + h] = ep;
  }
  __syncthreads();

  // ---- flush: lane owns row t again ----
  {
    f4* yo = (f4*)(yl_g + r*16);
    #pragma unroll
    for (int j=0;j<4;j++){
      f4 v = *(const f4*)&s_y[l*SY_STRIDE + 4*j];
      v.x += xskip[4*j]; v.y += xskip[4*j+1]; v.z += xskip[4*j+2]; v.w += xskip[4*j+3];
      yo[j] = v;
    }
    f4* eo = (f4*)(ea_g + r*8);
    eo[0] = *(const f4*)&s_y[l*SY_STRIDE + 16];
    eo[1] = *(const f4*)&s_y[l*SY_STRIDE + 20];
    f4* co = (f4*)(cm_g + r*8);
    co[0] = make_float4(cmv[0],cmv[1],cmv[2],cmv[3]);
    co[1] = make_float4(cmv[4],cmv[5],cmv[6],cmv[7]);
  }
}

// ---------------- K3: inter-chunk state prefix scan ----------------
// thread = (b,h,p,n) : 4096 threads, 64 sequential chunk steps
__global__ __launch_bounds__(256) void k3_chunkscan(
    const float* __restrict__ sloc_g, const float* __restrict__ p_g,
    float* __restrict__ sinit_g)
{
  int idx = blockIdx.x*256 + threadIdx.x;   // 0..4095
  int bh = idx >> 4, pn = idx & 15;
  float s = 0.f;
  #pragma unroll 8
  for (int c=0; c<NCHUNK; c++){
    size_t o = (size_t)c*256 + bh;
    float slc = sloc_g[o*16 + pn];
    float pc  = p_g[o];
    sinit_g[o*16 + pn] = s;                 // state at chunk START
    s = pc*s + slc;
  }
}

// ---------------- K4: finalize per row ----------------
__global__ __launch_bounds__(256) void k4_final(
    const float* __restrict__ yl_g, const float* __restrict__ ea_g,
    const float* __restrict__ cm_g, const float* __restrict__ z_g,
    const float* __restrict__ sinit_g,
    const float* __restrict__ norm_w, const float* __restrict__ out_proj,
    const float* __restrict__ W_out, const float* __restrict__ b_out,
    float* __restrict__ out)
{
  int r = blockIdx.x*256 + threadIdx.x;
  int t = r >> 5, b = r & 31, c = t >> 6;
  float y[16], cm[8], ea[8];
  {
    const f4* yp = (const f4*)(yl_g + (size_t)r*16);
    #pragma unroll
    for (int j=0;j<4;j++){ f4 v=yp[j]; y[4*j]=v.x; y[4*j+1]=v.y; y[4*j+2]=v.z; y[4*j+3]=v.w; }
    const f4* cp = (const f4*)(cm_g + (size_t)r*8);
    f4 c0=cp[0], c1=cp[1];
    cm[0]=c0.x; cm[1]=c0.y; cm[2]=c0.z; cm[3]=c0.w; cm[4]=c1.x; cm[5]=c1.y; cm[6]=c1.z; cm[7]=c1.w;
    const f4* epp = (const f4*)(ea_g + (size_t)r*8);
    f4 e0=epp[0], e1=epp[1];
    ea[0]=e0.x; ea[1]=e0.y; ea[2]=e0.z; ea[3]=e0.w; ea[4]=e1.x; ea[5]=e1.y; ea[6]=e1.z; ea[7]=e1.w;
  }
  // y += exp(cumA_t) * (C_t . S_init)
  {
    const float* sb = sinit_g + (size_t)c*4096 + (size_t)b*128;
    #pragma unroll
    for (int h=0; h<8; h++){
      f4 a0 = *(const f4*)(sb + h*16);
      f4 a1 = *(const f4*)(sb + h*16 + 4);
      f4 b0 = *(const f4*)(sb + h*16 + 8);
      f4 b1 = *(const f4*)(sb + h*16 + 12);
      float d0 = cm[0]*a0.x + cm[1]*a0.y + cm[2]*a0.z + cm[3]*a0.w
               + cm[4]*a1.x + cm[5]*a1.y + cm[6]*a1.z + cm[7]*a1.w;
      float d1 = cm[0]*b0.x + cm[1]*b0.y + cm[2]*b0.z + cm[3]*b0.w
               + cm[4]*b1.x + cm[5]*b1.y + cm[6]*b1.z + cm[7]*b1.w;
      y[2*h]   += ea[h]*d0;
      y[2*h+1] += ea[h]*d1;
    }
  }
  // gate, RMSNorm
  float g[16];
  {
    const f4* zp = (const f4*)(z_g + (size_t)r*16);
    #pragma unroll
    for (int j=0;j<4;j++){
      f4 v = zp[j];
      g[4*j]   = y[4*j]  *fsilu(v.x);
      g[4*j+1] = y[4*j+1]*fsilu(v.y);
      g[4*j+2] = y[4*j+2]*fsilu(v.z);
      g[4*j+3] = y[4*j+3]*fsilu(v.w);
    }
  }
  float ss = 0.f;
  #pragma unroll
  for (int i=0;i<16;i++) ss += g[i]*g[i];
  float rinv = rsqrtf(ss*(1.f/16.f) + 1e-5f);
  float gn[16];
  #pragma unroll
  for (int i=0;i<16;i++) gn[i] = g[i]*rinv*norm_w[i];
  float ro[16];
  #pragma unroll
  for (int j=0;j<16;j++){
    float a = 0.f;
    #pragma unroll
    for (int i=0;i<16;i++) a += gn[i]*out_proj[j*16+i];
    ro[j] = a > 0.f ? a : 0.f;
  }
  f4* oo = (f4*)(out + (size_t)r*16);
  #pragma unroll
  for (int q=0;q<4;q++){
    float lo[4];
    #pragma unroll
    for (int kk=0;kk<4;kk++){
      int k = q*4+kk;
      float a = b_out[k];
      #pragma unroll
      for (int j=0;j<16;j++) a += ro[j]*W_out[k*16+j];
      lo[kk] = a;
    }
    oo[q] = make_float4(lo[0],lo[1],lo[2],lo[3]);
  }
}

extern "C" void kernel_launch(void* const* d_in, const int* in_sizes, int n_in,
                              void* d_out, int out_size, void* d_ws, size_t ws_size,
                              hipStream_t stream)
{
  const float* obs     = (const float*)d_in[0];
  const float* W_in    = (const float*)d_in[1];
  const float* b_in    = (const float*)d_in[2];
  const float* in_proj = (const float*)d_in[3];
  const float* conv_w  = (const float*)d_in[4];
  const float* conv_b  = (const float*)d_in[5];
  const float* dt_bias = (const float*)d_in[6];
  const float* A_log   = (const float*)d_in[7];
  const float* D_skip  = (const float*)d_in[8];
  const float* norm_w  = (const float*)d_in[9];
  const float* out_prj = (const float*)d_in[10];
  const float* W_out   = (const float*)d_in[11];
  const float* b_out   = (const float*)d_in[12];
  float* out = (float*)d_out;

  float* ws     = (float*)d_ws;
  float* z_g    = ws;                               // 131072*16
  float* xbc_g  = z_g    + (size_t)NROWS*16;        // 131072*32
  float* dt_g   = xbc_g  + (size_t)NROWS*32;        // 131072*8
  float* yl_g   = dt_g   + (size_t)NROWS*8;         // 131072*16
  float* ea_g   = yl_g   + (size_t)NROWS*16;        // 131072*8
  float* cm_g   = ea_g   + (size_t)NROWS*8;         // 131072*8
  float* sloc_g = cm_g   + (size_t)NROWS*8;         // 64*256*16
  float* p_g    = sloc_g + (size_t)NCHUNK*256*16;   // 64*256
  float* sinit_g= p_g    + (size_t)NCHUNK*256;      // 64*256*16

  k1_proj<<<NROWS/256, 256, 0, stream>>>(obs, W_in, b_in, in_proj, dt_bias, z_g, xbc_g, dt_g);
  k2_scan<<<BATCHN*NCHUNK, 64, 0, stream>>>(xbc_g, dt_g, conv_w, conv_b, A_log, D_skip,
                                            yl_g, ea_g, cm_g, sloc_g, p_g);
  k3_chunkscan<<<16, 256, 0, stream>>>(sloc_g, p_g, sinit_g);
  k4_final<<<NROWS/256, 256, 0, stream>>>(yl_g, ea_g, cm_g, z_g, sinit_g,
                                          norm_w, out_prj, W_out, b_out, out);
}

// Round 10
// 151.396 us; speedup vs baseline: 1.0251x; 1.0251x over previous
//
#include <hip/hip_runtime.h>

#define T_LEN  4096
#define BATCHN 32
#define NROWS  (T_LEN*BATCHN)   // 131072
#define CHUNKL 64
#define NCHUNK (T_LEN/CHUNKL)   // 64

// s_in rows: staging phase holds raw xBC [0..31]; scan phase holds
//   [0..15]=B/C interleaved, [16+4h+{0,1,2}]={xdt0,xdt1,dA}, [16+4h+3]=pad (48 floats)
#define SIN_STRIDE 52
#define SY_STRIDE  28

typedef float4 f4;

__device__ __forceinline__ float fsilu(float x){ return x / (1.f + __expf(-x)); }
__device__ __forceinline__ float fsoftplus(float x){ return (x > 20.f) ? x : log1pf(__expf(x)); }

// 8-lane group sum via xor butterfly (groups = lanes [8k..8k+7]); direction-free.
__device__ __forceinline__ float group8_sum(float v){
  v += __shfl_xor(v, 1);
  v += __shfl_xor(v, 2);
  v += __shfl_xor(v, 4);
  return v;
}

// ---------------- F12: per-row proj + conv + within-chunk scan (fused K1+K2) ----------------
// one wave per (b, chunk). Lane l owns row t=c*64+l for proj/conv/flush; scan lane = h*8+n.
__global__ __launch_bounds__(64) void f12_scan(
    const float* __restrict__ obs, const float* __restrict__ W_in,
    const float* __restrict__ b_in, const float* __restrict__ in_proj,
    const float* __restrict__ dt_bias,
    const float* __restrict__ conv_w, const float* __restrict__ conv_b,
    const float* __restrict__ A_log, const float* __restrict__ D_skip,
    float* __restrict__ z_g, float* __restrict__ yl_g,
    float* __restrict__ ea_g, float* __restrict__ cm_g,
    float* __restrict__ sloc_g, float* __restrict__ p_g)
{
  __shared__ float s_in[CHUNKL*SIN_STRIDE];
  __shared__ float s_y[CHUNKL*SY_STRIDE];   // scratch: halo staging, later scan output
  int bid = blockIdx.x;
  int b = bid & 31, c = bid >> 5;
  int l = threadIdx.x;
  int t = c*CHUNKL + l;
  size_t r = (size_t)t*BATCHN + b;

  // ---- own-row input projection (was K1) ----
  float o[32];
  {
    const f4* op = (const f4*)(obs + r*32);
    #pragma unroll
    for (int j=0;j<8;j++){ f4 v = op[j]; o[4*j]=v.x; o[4*j+1]=v.y; o[4*j+2]=v.z; o[4*j+3]=v.w; }
  }
  float x[16];
  #pragma unroll
  for (int i=0;i<16;i++){
    float a = b_in[i];
    #pragma unroll
    for (int k=0;k<32;k++) a += o[k]*W_in[i*32+k];
    x[i] = a > 0.f ? a : 0.f;
  }
  float acc[56];
  #pragma unroll
  for (int j=0;j<56;j++){
    float a = 0.f;
    #pragma unroll
    for (int k=0;k<16;k++) a += x[k]*in_proj[j*16+k];
    acc[j] = a;
  }
  // z out (needed by K4)
  {
    f4* zo = (f4*)(z_g + (size_t)r*16);
    #pragma unroll
    for (int j=0;j<4;j++) zo[j] = make_float4(acc[4*j],acc[4*j+1],acc[4*j+2],acc[4*j+3]);
  }
  float dtv[8];
  #pragma unroll
  for (int k=0;k<8;k++) dtv[k] = fsoftplus(acc[48+k] + dt_bias[k]);

  // ---- stage raw xBC in s_in[l][0..31]; stage halo obs row in s_y[0..31] ----
  {
    f4* sr = (f4*)&s_in[l*SIN_STRIDE];
    #pragma unroll
    for (int j=0;j<8;j++) sr[j] = make_float4(acc[16+4*j],acc[17+4*j],acc[18+4*j],acc[19+4*j]);
  }
  if (c > 0 && l < 32){
    size_t rh = ((size_t)(c*CHUNKL) - 1)*BATCHN + b;   // row t = c*64-1
    s_y[l] = obs[rh*32 + l];
  }
  __syncthreads();

  // ---- halo projection (row c*64-1), cooperative (was K1 for that row) ----
  if (c > 0 && l < 16){
    float a = b_in[l];
    #pragma unroll
    for (int k=0;k<32;k++) a += s_y[k]*W_in[l*32+k];
    s_y[32+l] = a > 0.f ? a : 0.f;
  }
  __syncthreads();
  if (c > 0 && l < 32){
    float a = 0.f;
    #pragma unroll
    for (int k=0;k<16;k++) a += s_y[32+k]*in_proj[(16+l)*16+k];
    s_y[48+l] = a;
  }
  __syncthreads();

  // ---- read previous row's raw xBC ----
  float pv[32];
  if (t == 0){
    #pragma unroll
    for (int j=0;j<32;j++) pv[j]=0.f;
  } else if (l == 0){
    #pragma unroll
    for (int j=0;j<8;j++){ f4 v = *(const f4*)&s_y[48+4*j]; pv[4*j]=v.x; pv[4*j+1]=v.y; pv[4*j+2]=v.z; pv[4*j+3]=v.w; }
  } else {
    #pragma unroll
    for (int j=0;j<8;j++){ f4 v = *(const f4*)&s_in[(l-1)*SIN_STRIDE + 4*j]; pv[4*j]=v.x; pv[4*j+1]=v.y; pv[4*j+2]=v.z; pv[4*j+3]=v.w; }
  }
  __syncthreads();   // all pv reads done before s_in overwrite

  // ---- conv + silu, build scan row, overwrite s_in[l][0..47] ----
  float sv[32];
  #pragma unroll
  for (int ch=0; ch<32; ch++){
    float cv = conv_b[ch] + pv[ch]*conv_w[ch*2] + acc[16+ch]*conv_w[ch*2+1];
    sv[ch] = fsilu(cv);
  }
  float xskip[16], cmv[8];
  #pragma unroll
  for (int i=0;i<16;i++) xskip[i] = sv[i]*D_skip[i>>1];
  #pragma unroll
  for (int n=0;n<8;n++) cmv[n] = sv[24+n];
  {
    float row[48];
    #pragma unroll
    for (int n=0;n<8;n++){ row[2*n]=sv[16+n]; row[2*n+1]=sv[24+n]; }
    #pragma unroll
    for (int h=0;h<8;h++){
      float dth = dtv[h];
      row[16+4*h]   = sv[2*h]*dth;
      row[16+4*h+1] = sv[2*h+1]*dth;
      row[16+4*h+2] = __expf(-__expf(A_log[h])*dth);
      row[16+4*h+3] = 0.f;
    }
    f4* sr = (f4*)&s_in[l*SIN_STRIDE];
    #pragma unroll
    for (int j=0;j<12;j++) sr[j] = make_float4(row[4*j],row[4*j+1],row[4*j+2],row[4*j+3]);
  }
  __syncthreads();

  // ---- scan: lane = h*8 + n ----
  int h = l >> 3, n = l & 7;
  float s0=0.f, s1=0.f, ep=1.f;
  #pragma unroll 8
  for (int tt=0; tt<CHUNKL; tt++){
    float2 bcv = *(const float2*)&s_in[tt*SIN_STRIDE + 2*n];   // B_n, C_n
    f4 xd = *(const f4*)&s_in[tt*SIN_STRIDE + 16 + 4*h];       // xdt0, xdt1, dA, pad
    s0 = xd.z*s0 + xd.x*bcv.x;
    s1 = xd.z*s1 + xd.y*bcv.x;
    float y0 = group8_sum(s0*bcv.y);
    float y1 = group8_sum(s1*bcv.y);
    ep *= xd.z;
    if (n == 0){
      *(float2*)&s_y[tt*SY_STRIDE + 2*h] = make_float2(y0, y1);
      s_y[tt*SY_STRIDE + 16 + h] = ep;
    }
  }
  // final chunk state + decay product
  {
    size_t sb = ((size_t)(c*32+b)*8 + h)*16 + n;
    sloc_g[sb]   = s0;
    sloc_g[sb+8] = s1;
    if (n == 0) p_g[(size_t)(c*32+b)*8 + h] = ep;
  }
  __syncthreads();

  // ---- flush: lane owns row t again ----
  {
    f4* yo = (f4*)(yl_g + r*16);
    #pragma unroll
    for (int j=0;j<4;j++){
      f4 v = *(const f4*)&s_y[l*SY_STRIDE + 4*j];
      v.x += xskip[4*j]; v.y += xskip[4*j+1]; v.z += xskip[4*j+2]; v.w += xskip[4*j+3];
      yo[j] = v;
    }
    f4* eo = (f4*)(ea_g + r*8);
    eo[0] = *(const f4*)&s_y[l*SY_STRIDE + 16];
    eo[1] = *(const f4*)&s_y[l*SY_STRIDE + 20];
    f4* co = (f4*)(cm_g + r*8);
    co[0] = make_float4(cmv[0],cmv[1],cmv[2],cmv[3]);
    co[1] = make_float4(cmv[4],cmv[5],cmv[6],cmv[7]);
  }
}

// ---------------- K3: inter-chunk state prefix scan ----------------
__global__ __launch_bounds__(256) void k3_chunkscan(
    const float* __restrict__ sloc_g, const float* __restrict__ p_g,
    float* __restrict__ sinit_g)
{
  int idx = blockIdx.x*256 + threadIdx.x;   // 0..4095
  int bh = idx >> 4, pn = idx & 15;
  float s = 0.f;
  #pragma unroll 8
  for (int c=0; c<NCHUNK; c++){
    size_t o = (size_t)c*256 + bh;
    float slc = sloc_g[o*16 + pn];
    float pc  = p_g[o];
    sinit_g[o*16 + pn] = s;                 // state at chunk START
    s = pc*s + slc;
  }
}

// ---------------- K4: finalize per row ----------------
__global__ __launch_bounds__(256) void k4_final(
    const float* __restrict__ yl_g, const float* __restrict__ ea_g,
    const float* __restrict__ cm_g, const float* __restrict__ z_g,
    const float* __restrict__ sinit_g,
    const float* __restrict__ norm_w, const float* __restrict__ out_proj,
    const float* __restrict__ W_out, const float* __restrict__ b_out,
    float* __restrict__ out)
{
  int r = blockIdx.x*256 + threadIdx.x;
  int t = r >> 5, b = r & 31, c = t >> 6;
  float y[16], cm[8], ea[8];
  {
    const f4* yp = (const f4*)(yl_g + (size_t)r*16);
    #pragma unroll
    for (int j=0;j<4;j++){ f4 v=yp[j]; y[4*j]=v.x; y[4*j+1]=v.y; y[4*j+2]=v.z; y[4*j+3]=v.w; }
    const f4* cp = (const f4*)(cm_g + (size_t)r*8);
    f4 c0=cp[0], c1=cp[1];
    cm[0]=c0.x; cm[1]=c0.y; cm[2]=c0.z; cm[3]=c0.w; cm[4]=c1.x; cm[5]=c1.y; cm[6]=c1.z; cm[7]=c1.w;
    const f4* epp = (const f4*)(ea_g + (size_t)r*8);
    f4 e0=epp[0], e1=epp[1];
    ea[0]=e0.x; ea[1]=e0.y; ea[2]=e0.z; ea[3]=e0.w; ea[4]=e1.x; ea[5]=e1.y; ea[6]=e1.z; ea[7]=e1.w;
  }
  {
    const float* sb = sinit_g + (size_t)c*4096 + (size_t)b*128;
    #pragma unroll
    for (int h=0; h<8; h++){
      f4 a0 = *(const f4*)(sb + h*16);
      f4 a1 = *(const f4*)(sb + h*16 + 4);
      f4 b0 = *(const f4*)(sb + h*16 + 8);
      f4 b1 = *(const f4*)(sb + h*16 + 12);
      float d0 = cm[0]*a0.x + cm[1]*a0.y + cm[2]*a0.z + cm[3]*a0.w
               + cm[4]*a1.x + cm[5]*a1.y + cm[6]*a1.z + cm[7]*a1.w;
      float d1 = cm[0]*b0.x + cm[1]*b0.y + cm[2]*b0.z + cm[3]*b0.w
               + cm[4]*b1.x + cm[5]*b1.y + cm[6]*b1.z + cm[7]*b1.w;
      y[2*h]   += ea[h]*d0;
      y[2*h+1] += ea[h]*d1;
    }
  }
  float g[16];
  {
    const f4* zp = (const f4*)(z_g + (size_t)r*16);
    #pragma unroll
    for (int j=0;j<4;j++){
      f4 v = zp[j];
      g[4*j]   = y[4*j]  *fsilu(v.x);
      g[4*j+1] = y[4*j+1]*fsilu(v.y);
      g[4*j+2] = y[4*j+2]*fsilu(v.z);
      g[4*j+3] = y[4*j+3]*fsilu(v.w);
    }
  }
  float ss = 0.f;
  #pragma unroll
  for (int i=0;i<16;i++) ss += g[i]*g[i];
  float rinv = rsqrtf(ss*(1.f/16.f) + 1e-5f);
  float gn[16];
  #pragma unroll
  for (int i=0;i<16;i++) gn[i] = g[i]*rinv*norm_w[i];
  float ro[16];
  #pragma unroll
  for (int j=0;j<16;j++){
    float a = 0.f;
    #pragma unroll
    for (int i=0;i<16;i++) a += gn[i]*out_proj[j*16+i];
    ro[j] = a > 0.f ? a : 0.f;
  }
  f4* oo = (f4*)(out + (size_t)r*16);
  #pragma unroll
  for (int q=0;q<4;q++){
    float lo[4];
    #pragma unroll
    for (int kk=0;kk<4;kk++){
      int k = q*4+kk;
      float a = b_out[k];
      #pragma unroll
      for (int j=0;j<16;j++) a += ro[j]*W_out[k*16+j];
      lo[kk] = a;
    }
    oo[q] = make_float4(lo[0],lo[1],lo[2],lo[3]);
  }
}

extern "C" void kernel_launch(void* const* d_in, const int* in_sizes, int n_in,
                              void* d_out, int out_size, void* d_ws, size_t ws_size,
                              hipStream_t stream)
{
  const float* obs     = (const float*)d_in[0];
  const float* W_in    = (const float*)d_in[1];
  const float* b_in    = (const float*)d_in[2];
  const float* in_proj = (const float*)d_in[3];
  const float* conv_w  = (const float*)d_in[4];
  const float* conv_b  = (const float*)d_in[5];
  const float* dt_bias = (const float*)d_in[6];
  const float* A_log   = (const float*)d_in[7];
  const float* D_skip  = (const float*)d_in[8];
  const float* norm_w  = (const float*)d_in[9];
  const float* out_prj = (const float*)d_in[10];
  const float* W_out   = (const float*)d_in[11];
  const float* b_out   = (const float*)d_in[12];
  float* out = (float*)d_out;

  float* ws     = (float*)d_ws;
  float* z_g    = ws;                               // 131072*16
  float* yl_g   = z_g    + (size_t)NROWS*16;        // 131072*16
  float* ea_g   = yl_g   + (size_t)NROWS*16;        // 131072*8
  float* cm_g   = ea_g   + (size_t)NROWS*8;         // 131072*8
  float* sloc_g = cm_g   + (size_t)NROWS*8;         // 64*256*16
  float* p_g    = sloc_g + (size_t)NCHUNK*256*16;   // 64*256
  float* sinit_g= p_g    + (size_t)NCHUNK*256;      // 64*256*16

  f12_scan<<<BATCHN*NCHUNK, 64, 0, stream>>>(obs, W_in, b_in, in_proj, dt_bias,
                                             conv_w, conv_b, A_log, D_skip,
                                             z_g, yl_g, ea_g, cm_g, sloc_g, p_g);
  k3_chunkscan<<<16, 256, 0, stream>>>(sloc_g, p_g, sinit_g);
  k4_final<<<NROWS/256, 256, 0, stream>>>(yl_g, ea_g, cm_g, z_g, sinit_g,
                                          norm_w, out_prj, W_out, b_out, out);
}